// Round 2
// baseline (818.141 us; speedup 1.0000x reference)
//
#include <hip/hip_runtime.h>

// Problem constants (B=1 folded out)
constexpr int C  = 64;
constexpr int D  = 64;
constexpr int H  = 128;
constexpr int W  = 128;
constexpr int ZS = H * W;       // 16384   (z stride, elements)
constexpr int YS = W;           // 128     (y stride)
constexpr int CS = D * H * W;   // 1048576 (channel stride)

// Native clang vector type: accepted by __builtin_nontemporal_{load,store}
// (HIP's float4 is a class and is rejected).
typedef float f4 __attribute__((ext_vector_type(4)));

// One thread computes 4 consecutive x outputs for all 27 displacement taps.
// ALL global loads are branch-free: out-of-range (zz,yy) rows are handled by
// clamping the address into the valid tensor (load is always legal) and
// multiplying the in1 fragment by a 0/1 row mask, so every product of that
// row contributes exactly 0. This removes the divergent if/else that was
// serializing the memory pipeline (1-2 loads in flight -> latency bound at
// 15% HBM BW). Each channel iteration now issues 28 independent loads
// before any use.
__global__ __launch_bounds__(256, 2)
void corr3d_kernel(const float* __restrict__ in1,
                   const float* __restrict__ in2,
                   float* __restrict__ out) {
    const int tx = threadIdx.x;           // 0..31 -> x0 = 4*tx
    const int ty = threadIdx.y;           // 0..7
    const int x0 = tx * 4;
    const int y  = blockIdx.x * 8 + ty;   // 0..127
    const int z  = blockIdx.y;            // 0..63

    float acc[27][4];
#pragma unroll
    for (int j = 0; j < 27; ++j) {
#pragma unroll
        for (int i = 0; i < 4; ++i) acc[j][i] = 0.0f;
    }

    // Per-row (dz,dy) descriptors: clamped base offset + 0/1 validity mask.
    int   rowoff[9];
    float rowmask[9];
#pragma unroll
    for (int dz = 0; dz < 3; ++dz) {
        const int zz  = z + dz - 1;
        const int zzc = min(max(zz, 0), D - 1);
        const bool zok = ((unsigned)zz < (unsigned)D);
#pragma unroll
        for (int dy = 0; dy < 3; ++dy) {
            const int yy  = y + dy - 1;
            const int yyc = min(max(yy, 0), H - 1);
            const bool ok = zok && ((unsigned)yy < (unsigned)H);
            const int r = dz * 3 + dy;
            rowoff[r]  = zzc * ZS + yyc * YS + x0;
            rowmask[r] = ok ? 1.0f : 0.0f;
        }
    }

    // x-edge taps: clamped offsets (always in-bounds) + 0/1 masks.
    const bool xlo = (x0 > 0);
    const bool xhi = (x0 < W - 4);
    const int   offm = xlo ? -1 : 0;
    const int   offp = xhi ?  4 : 3;
    const float mlo  = xlo ? 1.0f : 0.0f;
    const float mhi  = xhi ? 1.0f : 0.0f;

    const float* p1 = in1 + z * ZS + y * YS + x0;

    for (int c = 0; c < C; ++c) {
        const float* b2 = in2 + c * CS;

        // in1 fragment: touched by exactly one block -> non-temporal.
        const f4 a = __builtin_nontemporal_load((const f4*)(p1 + c * CS));

        // ---- load phase: 27 independent in2 loads, no branches ----
        f4    m[9];
        float vl[9], vr[9];
#pragma unroll
        for (int r = 0; r < 9; ++r) {
            const float* p = b2 + rowoff[r];
            m[r]  = *(const f4*)p;
            vl[r] = p[offm];
            vr[r] = p[offp];
        }

        // ---- compute phase: 108 FMAs + masking ----
#pragma unroll
        for (int r = 0; r < 9; ++r) {
            const float msk = rowmask[r];
            const float ax = a.x * msk, ay = a.y * msk,
                        az = a.z * msk, aw = a.w * msk;
            const float v0 = vl[r] * mlo;
            const float v1 = m[r].x, v2 = m[r].y, v3 = m[r].z, v4 = m[r].w;
            const float v5 = vr[r] * mhi;
            const int jb = r * 3;

            acc[jb + 0][0] += ax * v0;
            acc[jb + 0][1] += ay * v1;
            acc[jb + 0][2] += az * v2;
            acc[jb + 0][3] += aw * v3;

            acc[jb + 1][0] += ax * v1;
            acc[jb + 1][1] += ay * v2;
            acc[jb + 1][2] += az * v3;
            acc[jb + 1][3] += aw * v4;

            acc[jb + 2][0] += ax * v2;
            acc[jb + 2][1] += ay * v3;
            acc[jb + 2][2] += az * v4;
            acc[jb + 2][3] += aw * v5;
        }
    }

    const float s = 1.0f / (float)C;  // channel mean
    float* po = out + z * ZS + y * YS + x0;
#pragma unroll
    for (int j = 0; j < 27; ++j) {
        f4 o;
        o.x = acc[j][0] * s;
        o.y = acc[j][1] * s;
        o.z = acc[j][2] * s;
        o.w = acc[j][3] * s;
        // out is written once and never re-read -> non-temporal store.
        __builtin_nontemporal_store(o, (f4*)(po + (size_t)j * CS));
    }
}

extern "C" void kernel_launch(void* const* d_in, const int* in_sizes, int n_in,
                              void* d_out, int out_size, void* d_ws, size_t ws_size,
                              hipStream_t stream) {
    const float* in1 = (const float*)d_in[0];
    const float* in2 = (const float*)d_in[1];
    float* out = (float*)d_out;

    dim3 block(32, 8);        // 256 threads = 4 waves; wave = 2 y-rows
    dim3 grid(H / 8, D);      // (16 y-groups, 64 z)
    corr3d_kernel<<<grid, block, 0, stream>>>(in1, in2, out);
}